// Round 9
// baseline (144.301 us; speedup 1.0000x reference)
//
#include <hip/hip_runtime.h>

// ---------------------------------------------------------------------------
// KAN forward as one bf16 MFMA GEMM:
//   y[n,o] = sum_i ( silu(x[n,i])*scale_base[o,i]
//                  + sum_b basis_b(x[n,i]) * scale_sp[o,i]*coef[o,i,b] ) + bias[o]
// A[n, i*8+s], W[o, i*8+s]: s=0 -> (silu, scale_base); s=1..6 -> (basis, sp*coef);
// s=7 -> zero pad.  K = 512*8 = 4096.
// Round 9: r7 core (B direct from L2, A-LDS dbuf) with doubled TLP:
// 512 threads (8 waves 2Mx4N, wave tile 32x64, acc=32 VGPR), grid 512,
// 2 blocks/CU -> 4 waves/SIMD so act-VALU of some waves overlaps MFMA of
// others. B loads JIT per iter (no dbuf) to stay under 128 VGPR. setprio
// around MFMA cluster (phase-diverse waves -> T5 regime).
// ---------------------------------------------------------------------------

typedef short        bf16x8 __attribute__((ext_vector_type(8)));
typedef float        f32x4  __attribute__((ext_vector_type(4)));
typedef unsigned int u32x4  __attribute__((ext_vector_type(4)));

#define NROWS 16384
#define DIN   512
#define DOUT  512
#define BM    64
#define BN    256
#define NKT   64              // K-steps; each covers 8 input features (64 k-units)

__device__ __forceinline__ unsigned short f2bf(float f) {
    unsigned int u = __float_as_uint(f);
    u += 0x7fffu + ((u >> 16) & 1u);          // round-to-nearest-even
    return (unsigned short)(u >> 16);
}

// ---------------------------------------------------------------------------
// Lean activation store: one feature's 8-slot group at p16 (16B, swizzled base).
//   slot 0 = silu(x); slots 1..6 = basis_{0..5}(x); slot 7 = pad (W==0).
// Cell-local eval: S = 1.5x+4.5, j = floor(S), t = S-j in [0,1).
// Nonzero splines: basis_{j-3+m} = n_m(t), m=0..3. Out-of-range -> slot 7.
// ---------------------------------------------------------------------------
__device__ __forceinline__ void kan_act_store(float xv, char* p16) {
    float S  = __builtin_fmaf(xv, 1.5f, 4.5f);
    float jf = floorf(S);
    float t  = S - jf;
    int   j  = (int)jf;
    float t2 = t * t;
    float t3 = t2 * t;
    float omt  = 1.0f - t;
    float omt2 = omt * omt;
    float n0 = omt2 * omt * (1.0f / 6.0f);                    // (1-t)^3/6
    float n1 = __builtin_fmaf(t3, 0.5f, -t2) + (2.0f / 3.0f); // (3t^3-6t^2+4)/6
    float u  = (t + t2) - t3;
    float n2 = __builtin_fmaf(u, 0.5f, 1.0f / 6.0f);          // (-3t^3+3t^2+3t+1)/6
    float n3 = t3 * (1.0f / 6.0f);                            // t^3/6
    float e  = __expf(-xv);
    float si = xv * __builtin_amdgcn_rcpf(1.0f + e);          // silu

    unsigned w01, w23, wsil;
    asm("v_cvt_pk_bf16_f32 %0, %1, %2" : "=v"(w01)  : "v"(n0), "v"(n1));
    asm("v_cvt_pk_bf16_f32 %0, %1, %2" : "=v"(w23)  : "v"(n2), "v"(n3));
    asm("v_cvt_pk_bf16_f32 %0, %1, %2" : "=v"(wsil) : "v"(si), "v"(0.0f));

    u32x4 init = {wsil, 0u, 0u, 0u};   // [silu, 0,0,0,0,0,0,0]
    *(u32x4*)p16 = init;

    unsigned short v0 = (unsigned short)w01, v1 = (unsigned short)(w01 >> 16);
    unsigned short v2 = (unsigned short)w23, v3 = (unsigned short)(w23 >> 16);
    int b0 = j - 3;
    int s0 = ((unsigned)(b0    ) <= 5u) ? (b0 + 1) : 7;
    int s1 = ((unsigned)(b0 + 1) <= 5u) ? (b0 + 2) : 7;
    int s2 = ((unsigned)(b0 + 2) <= 5u) ? (b0 + 3) : 7;
    int s3 = ((unsigned)(b0 + 3) <= 5u) ? (b0 + 4) : 7;
    *(unsigned short*)(p16 + 2 * s0) = v0;
    *(unsigned short*)(p16 + 2 * s1) = v1;
    *(unsigned short*)(p16 + 2 * s2) = v2;
    *(unsigned short*)(p16 + 2 * s3) = v3;
}

// ---------------------------------------------------------------------------
// Prep: pack W into ws as bf16 16B slot-groups, laid out so GEMM B-frag wave
// loads are contiguous:
//   byte = nt*2MB + ((kt*2 + ks)*256 + ol)*64 + fg*16
// where o = nt*256+ol, i = kt*8 + ks*4 + fg.
// ---------------------------------------------------------------------------
__global__ __launch_bounds__(256) void kan_prep(
    const float* __restrict__ coef, const float* __restrict__ scale_base,
    const float* __restrict__ scale_sp, unsigned short* __restrict__ wt)
{
    int t = blockIdx.x * 256 + threadIdx.x;   // t = o*512 + i
    int o = t >> 9;
    int i = t & 511;
    float sb = scale_base[t];
    float sp = scale_sp[t];
    const float* cp = coef + (size_t)t * 6;
    bf16x8 w;
    w[0] = (short)f2bf(sb);
#pragma unroll
    for (int b = 0; b < 6; ++b) w[1 + b] = (short)f2bf(sp * cp[b]);
    w[7] = 0;
    int nt = o >> 8, ol = o & 255;
    int kt = i >> 3, s = i & 7, ks = s >> 2, fg = s & 3;
    size_t off = (size_t)nt * 2097152
               + (size_t)((kt * 2 + ks) * 256 + ol) * 64 + fg * 16;
    *(bf16x8*)((char*)wt + off) = w;
}

// ---------------------------------------------------------------------------
// Fused GEMM: BM=64 x BN=256, BK=64 (8 features), 512 threads (8 waves 2Mx4N,
// wave tile 32x64 = 2x4 frags of 16x16x32). A in LDS dbuf (16KB); B global->reg.
// 2 blocks/CU, 4 waves/SIMD.
// ---------------------------------------------------------------------------
__global__ __launch_bounds__(512, 4) void kan_gemm(
    const float* __restrict__ x, const unsigned short* __restrict__ wt,
    const float* __restrict__ bias, float* __restrict__ y)
{
    __shared__ char As[2][BM * 128];   // 2 x 8 KB, swizzled rows of 64 bf16

    const int tid  = threadIdx.x;
    const int lane = tid & 63;
    const int wid  = tid >> 6;        // 0..7
    const int wm   = wid >> 2;        // 0..1
    const int wn   = wid & 3;         // 0..3

    // bijective XCD-aware swizzle: 512 wgs, 8 XCDs, contiguous 64-chunk each.
    // XCDs 0-3 -> nt=0, XCDs 4-7 -> nt=1: 2MB W-half stays L2-resident per XCD.
    int bid = blockIdx.x;
    int wg  = (bid & 7) * 64 + (bid >> 3);
    int mt  = wg & 255;
    int nt  = wg >> 8;

    const int row0 = mt * BM;
    const int col0 = nt * BN;

    // A staging: thread -> (row ar, feature ap); 1 act per thread per iter
    const int ar = tid >> 3;          // 0..63
    const int ap = tid & 7;           // 0..7
    const float* xp = x + (size_t)(row0 + ar) * DIN + ap;
    const int as_sw = (ar & 7) << 4;
    const int c0 = ap << 4;
    char* const arow0p = &As[0][ar * 128];
    char* const arow1p = &As[1][ar * 128];

    const int fr = lane & 15;         // fragment row/col
    const int fg = lane >> 4;         // k-group 0..3

    // B-frag bases: frag (ks, n2) at iter kt reads 16B from
    //   wb + (kt*2+ks)*16384 + colpart[n2],  colpart = (wn*64+n2*16+fr)*64 + fg*16
    // -> wave's 64 lanes (fr,fg) cover 1024 contiguous bytes (coalesced).
    const char* wb = (const char*)wt + (size_t)nt * 2097152;
    int colpart[4];
#pragma unroll
    for (int n2 = 0; n2 < 4; ++n2)
        colpart[n2] = (wn * 64 + n2 * 16 + fr) * 64 + fg * 16;

// load one ks-half (4 frags) of B for iter ktv
#define LOADB_H(B, ktv, ks_)                                                  \
    {                                                                         \
        const char* wkt_ = wb + (size_t)((ktv) * 2 + (ks_)) * 16384;          \
        _Pragma("unroll")                                                     \
        for (int n2_ = 0; n2_ < 4; ++n2_)                                     \
            B[n2_] = *(const bf16x8*)(wkt_ + colpart[n2_]);                   \
    }

    f32x4 acc[2][4];
#pragma unroll
    for (int m2 = 0; m2 < 2; ++m2)
#pragma unroll
        for (int n2 = 0; n2 < 4; ++n2) {
            f32x4 z = {0.f, 0.f, 0.f, 0.f};
            acc[m2][n2] = z;
        }

    // ---------------- prologue: acts(0) -> As[0] ----------------
    kan_act_store(xp[0], arow0p + (c0 ^ as_sw));
    float xb = xp[8];                 // x for kt=1
    asm volatile("s_waitcnt lgkmcnt(0)" ::: "memory");
    __builtin_amdgcn_s_barrier();

// one K-step: A-frag ds_reads first (latency under B-issue + acts), B JIT
// loads (L2; vmcnt counted by compiler, hidden by acts + other waves),
// act(kt+1) -> As[nxt], then 16 MFMA under setprio.
#define STEP(ktv)                                                             \
    {                                                                         \
        const int cur_ = (ktv) & 1;                                           \
        bf16x8 af_[2][2];                                                     \
        _Pragma("unroll")                                                     \
        for (int ks_ = 0; ks_ < 2; ++ks_) {                                   \
            _Pragma("unroll")                                                 \
            for (int m2_ = 0; m2_ < 2; ++m2_) {                               \
                int rr_ = wm * 32 + m2_ * 16 + fr;                            \
                af_[ks_][m2_] = *(const bf16x8*)(&As[cur_][0] + rr_ * 128     \
                    + ((ks_ * 64 + fg * 16) ^ ((rr_ & 7) << 4)));             \
            }                                                                 \
        }                                                                     \
        bf16x8 B0_[4], B1_[4];                                                \
        LOADB_H(B0_, ktv, 0);                                                 \
        LOADB_H(B1_, ktv, 1);                                                 \
        if ((ktv) + 1 < NKT) {                                                \
            char* rowp_ = (((ktv) + 1) & 1) ? arow1p : arow0p;                \
            kan_act_store(xb, rowp_ + (c0 ^ as_sw));                          \
            if ((ktv) + 2 < NKT) xb = xp[((ktv) + 2) * 8];                    \
        }                                                                     \
        __builtin_amdgcn_s_setprio(1);                                        \
        _Pragma("unroll")                                                     \
        for (int m2_ = 0; m2_ < 2; ++m2_)                                     \
            _Pragma("unroll")                                                 \
            for (int n2_ = 0; n2_ < 4; ++n2_)                                 \
                acc[m2_][n2_] = __builtin_amdgcn_mfma_f32_16x16x32_bf16(      \
                    af_[0][m2_], B0_[n2_], acc[m2_][n2_], 0, 0, 0);           \
        _Pragma("unroll")                                                     \
        for (int m2_ = 0; m2_ < 2; ++m2_)                                     \
            _Pragma("unroll")                                                 \
            for (int n2_ = 0; n2_ < 4; ++n2_)                                 \
                acc[m2_][n2_] = __builtin_amdgcn_mfma_f32_16x16x32_bf16(      \
                    af_[1][m2_], B1_[n2_], acc[m2_][n2_], 0, 0, 0);           \
        __builtin_amdgcn_s_setprio(0);                                        \
        asm volatile("s_waitcnt lgkmcnt(0)" ::: "memory");                    \
        __builtin_amdgcn_s_barrier();                                         \
    }

    for (int kt = 0; kt < NKT; kt += 2) {
        STEP(kt);
        STEP(kt + 1);
    }

    // ---- epilogue: C/D layout col = lane&15, row = (lane>>4)*4 + reg
    const int orow0 = row0 + wm * 32 + fg * 4;
    const int ocol0 = col0 + wn * 64 + fr;
#pragma unroll
    for (int n2 = 0; n2 < 4; ++n2) {
        float bv = bias[ocol0 + n2 * 16];
#pragma unroll
        for (int m2 = 0; m2 < 2; ++m2) {
#pragma unroll
            for (int r = 0; r < 4; ++r) {
                y[(size_t)(orow0 + m2 * 16 + r) * DOUT + (ocol0 + n2 * 16)]
                    = acc[m2][n2][r] + bv;
            }
        }
    }
#undef STEP
#undef LOADB_H
}

extern "C" void kernel_launch(void* const* d_in, const int* in_sizes, int n_in,
                              void* d_out, int out_size, void* d_ws, size_t ws_size,
                              hipStream_t stream)
{
    const float* x          = (const float*)d_in[0];
    const float* coef       = (const float*)d_in[1];
    const float* scale_base = (const float*)d_in[2];
    const float* scale_sp   = (const float*)d_in[3];
    const float* bias       = (const float*)d_in[4];
    unsigned short* wt = (unsigned short*)d_ws;   // 4 MB packed wt2[nt][kt][ks][ol][fg]
    float* y = (float*)d_out;

    kan_prep<<<1024, 256, 0, stream>>>(coef, scale_base, scale_sp, wt);
    kan_gemm<<<512, 512, 0, stream>>>(x, wt, bias, y);
}

// Round 10
// 81.730 us; speedup vs baseline: 1.7656x; 1.7656x over previous
//
#include <hip/hip_runtime.h>

// ---------------------------------------------------------------------------
// KAN forward as one bf16 MFMA GEMM:
//   y[n,o] = sum_i ( silu(x[n,i])*scale_base[o,i]
//                  + sum_b basis_b(x[n,i]) * scale_sp[o,i]*coef[o,i,b] ) + bias[o]
// A[n, i*8+s], W[o, i*8+s]: s=0 -> (silu, scale_base); s=1..6 -> (basis, sp*coef);
// s=7 -> zero pad.  K = 512*8 = 4096.
// Round 10: r7 structure frozen (BM=64/BN=256, 4 waves, 2 blocks/CU, B direct
// from L2 with dbuf prefetch, A-LDS dbuf). Act now builds its 16B slot-group
// entirely in registers (cvt_pk pairs + parity/base cndmask placement) and
// stores with ONE ds_write_b128 - kills the 4x ds_write_b16 scatter and its
// ~5M bank-conflict cycles. setprio(1) around MFMA cluster.
// ---------------------------------------------------------------------------

typedef short        bf16x8 __attribute__((ext_vector_type(8)));
typedef float        f32x4  __attribute__((ext_vector_type(4)));
typedef unsigned int u32x4  __attribute__((ext_vector_type(4)));

#define NROWS 16384
#define DIN   512
#define DOUT  512
#define BM    64
#define BN    256
#define NKT   64              // K-steps; each covers 8 input features (64 k-units)

__device__ __forceinline__ unsigned short f2bf(float f) {
    unsigned int u = __float_as_uint(f);
    u += 0x7fffu + ((u >> 16) & 1u);          // round-to-nearest-even
    return (unsigned short)(u >> 16);
}

// ---------------------------------------------------------------------------
// Register-built activation: 8 bf16 slots [silu, basis0..5, pad] for one x.
// Cell-local: S = 1.5x+4.5, j = floor(S), t = S-j; cardinal cubics n0..n3 land
// at slots j-2..j+1 (slot = basis index + 1). Placement done in registers:
//   even j: words (P01,P23) at word-base b=(j-2)>>1
//   odd  j: words (U,V,Z)   at word-base b          (16-bit-shifted variants)
// slot0 always overwritten by silu (absorbs the b=-1 clip); slot7 spillover is
// harmless (W pad = 0); out-of-range j -> all-zero. Single ds_write_b128.
// ---------------------------------------------------------------------------
__device__ __forceinline__ void kan_act_store(float xv, char* p16) {
    float S  = __builtin_fmaf(xv, 1.5f, 4.5f);
    float jf = floorf(S);
    float t  = S - jf;
    int   j  = (int)jf;
    float t2 = t * t;
    float t3 = t2 * t;
    float omt  = 1.0f - t;
    float omt2 = omt * omt;
    float n0 = omt2 * omt * (1.0f / 6.0f);                    // (1-t)^3/6
    float n1 = __builtin_fmaf(t3, 0.5f, -t2) + (2.0f / 3.0f); // (3t^3-6t^2+4)/6
    float u  = (t + t2) - t3;
    float n2 = __builtin_fmaf(u, 0.5f, 1.0f / 6.0f);          // (-3t^3+3t^2+3t+1)/6
    float n3 = t3 * (1.0f / 6.0f);                            // t^3/6
    float e  = __expf(-xv);
    float si = xv * __builtin_amdgcn_rcpf(1.0f + e);          // silu

    unsigned P01, P23, WS;
    asm("v_cvt_pk_bf16_f32 %0, %1, %2" : "=v"(P01) : "v"(n0), "v"(n1));
    asm("v_cvt_pk_bf16_f32 %0, %1, %2" : "=v"(P23) : "v"(n2), "v"(n3));
    asm("v_cvt_pk_bf16_f32 %0, %1, %2" : "=v"(WS)  : "v"(si), "v"(0.0f));
    unsigned U = P01 << 16;                      // (0 , n0)
    unsigned V = (P01 >> 16) | (P23 << 16);      // (n1, n2)
    unsigned Z = P23 >> 16;                      // (n3, 0 )
    bool odd = (j & 1) != 0;
    unsigned c0 = odd ? U : P01;
    unsigned c1 = odd ? V : P23;
    unsigned c2 = odd ? Z : 0u;
    int b = (j - 2) >> 1;                        // arithmetic shift (floor)
    u32x4 w;
    w[0] = (b == 0) ? c0 : (b == -1) ? c1 : (b == -2) ? c2 : 0u;
    w[1] = (b == 1) ? c0 : (b ==  0) ? c1 : (b == -1) ? c2 : 0u;
    w[2] = (b == 2) ? c0 : (b ==  1) ? c1 : (b ==  0) ? c2 : 0u;
    w[3] = (b == 3) ? c0 : (b ==  2) ? c1 : (b ==  1) ? c2 : 0u;
    w[0] = (w[0] & 0xFFFF0000u) | (WS & 0xFFFFu);   // silu -> slot 0
    *(u32x4*)p16 = w;
}

// ---------------------------------------------------------------------------
// Prep: pack W into ws as bf16 16B slot-groups, laid out so GEMM B-frag wave
// loads are contiguous:
//   byte = nt*2MB + ((kt*2 + ks)*256 + ol)*64 + fg*16
// where o = nt*256+ol, i = kt*8 + ks*4 + fg.
// ---------------------------------------------------------------------------
__global__ __launch_bounds__(256) void kan_prep(
    const float* __restrict__ coef, const float* __restrict__ scale_base,
    const float* __restrict__ scale_sp, unsigned short* __restrict__ wt)
{
    int t = blockIdx.x * 256 + threadIdx.x;   // t = o*512 + i
    int o = t >> 9;
    int i = t & 511;
    float sb = scale_base[t];
    float sp = scale_sp[t];
    const float* cp = coef + (size_t)t * 6;
    bf16x8 w;
    w[0] = (short)f2bf(sb);
#pragma unroll
    for (int b = 0; b < 6; ++b) w[1 + b] = (short)f2bf(sp * cp[b]);
    w[7] = 0;
    int nt = o >> 8, ol = o & 255;
    int kt = i >> 3, s = i & 7, ks = s >> 2, fg = s & 3;
    size_t off = (size_t)nt * 2097152
               + (size_t)((kt * 2 + ks) * 256 + ol) * 64 + fg * 16;
    *(bf16x8*)((char*)wt + off) = w;
}

// ---------------------------------------------------------------------------
// Fused GEMM: BM=64 x BN=256, BK=64 (8 features), 256 threads (4 waves, wave
// tile 64x64 = 4x4 frags of 16x16x32). A in LDS dbuf (16KB); B global->reg.
// ---------------------------------------------------------------------------
__global__ __launch_bounds__(256, 2) void kan_gemm(
    const float* __restrict__ x, const unsigned short* __restrict__ wt,
    const float* __restrict__ bias, float* __restrict__ y)
{
    __shared__ char As[2][BM * 128];   // 2 x 8 KB, swizzled rows of 64 bf16

    const int tid  = threadIdx.x;
    const int lane = tid & 63;
    const int wid  = tid >> 6;        // 0..3 (= wn)

    // bijective XCD-aware swizzle: 512 wgs, 8 XCDs, contiguous 64-chunk each.
    // XCDs 0-3 -> nt=0, XCDs 4-7 -> nt=1: 2MB W-half stays L2-resident per XCD.
    int bid = blockIdx.x;
    int wg  = (bid & 7) * 64 + (bid >> 3);
    int mt  = wg & 255;
    int nt  = wg >> 8;

    const int row0 = mt * BM;
    const int col0 = nt * BN;

    // A staging: thread -> (row ar, feature-pair ap)
    const int ar = tid >> 2;          // 0..63
    const int ap = tid & 3;           // 0..3
    const float* xp = x + (size_t)(row0 + ar) * DIN + ap * 2;
    const int as_sw = (ar & 7) << 4;
    const int c0 = (ap * 2) << 4;

    const int fr = lane & 15;         // fragment row/col
    const int fg = lane >> 4;         // k-group 0..3

    // B-frag bases: frag (ks, n2) at iter kt reads 16B from
    //   wb + (kt*2+ks)*16384 + colpart[n2],  colpart = (wid*64+n2*16+fr)*64 + fg*16
    // -> wave's 64 lanes (fr,fg) cover 1024 contiguous bytes (coalesced).
    const char* wb = (const char*)wt + (size_t)nt * 2097152;
    int colpart[4];
#pragma unroll
    for (int n2 = 0; n2 < 4; ++n2)
        colpart[n2] = (wid * 64 + n2 * 16 + fr) * 64 + fg * 16;

#define LOADB(B, ktv)                                                         \
    {                                                                         \
        _Pragma("unroll")                                                     \
        for (int q = 0; q < 8; ++q) {                                         \
            int n2_ = q & 3, ks_ = q >> 2;                                    \
            B[q] = *(const bf16x8*)(wb + (size_t)((ktv) * 2 + ks_) * 16384    \
                                    + colpart[n2_]);                          \
        }                                                                     \
    }

    f32x4 acc[4][4];
#pragma unroll
    for (int m2 = 0; m2 < 4; ++m2)
#pragma unroll
        for (int n2 = 0; n2 < 4; ++n2) {
            f32x4 z = {0.f, 0.f, 0.f, 0.f};
            acc[m2][n2] = z;
        }

    bf16x8 Ba[8], Bb[8];

    // ---------------- prologue: B(0) -> Ba, acts(0) -> As[0] ----------------
    LOADB(Ba, 0);
    {
        float2 xa = *(const float2*)(xp);
        char* rowp = &As[0][ar * 128];
        kan_act_store(xa.x, rowp + (c0 ^ as_sw));
        kan_act_store(xa.y, rowp + ((c0 + 16) ^ as_sw));
    }
    float2 xb = *(const float2*)(xp + 8);     // x for kt=1
    asm volatile("s_waitcnt lgkmcnt(0)" ::: "memory");
    __builtin_amdgcn_s_barrier();

// one K-step: consume Bcur + As[ktv&1]; produce Bnext + As[(ktv+1)&1].
// A-frag ds_reads issued first (latency hides under acts' VALU); MFMA's use
// of Bcur gets a compiler-counted vmcnt (Bnext's 8 loads stay in flight).
#define STEP(ktv, Bcur, Bnext)                                                \
    {                                                                         \
        const int cur_ = (ktv) & 1, nxt_ = cur_ ^ 1;                          \
        bf16x8 af_[2][4];                                                     \
        _Pragma("unroll")                                                     \
        for (int ks_ = 0; ks_ < 2; ++ks_) {                                   \
            _Pragma("unroll")                                                 \
            for (int m2_ = 0; m2_ < 4; ++m2_) {                               \
                int rr_ = m2_ * 16 + fr;                                      \
                af_[ks_][m2_] = *(const bf16x8*)(&As[cur_][0] + rr_ * 128     \
                    + ((ks_ * 64 + fg * 16) ^ ((rr_ & 7) << 4)));             \
            }                                                                 \
        }                                                                     \
        if ((ktv) + 1 < NKT) {                                                \
            LOADB(Bnext, (ktv) + 1);                                          \
            char* rowp_ = &As[nxt_][ar * 128];                                \
            kan_act_store(xb.x, rowp_ + (c0 ^ as_sw));                        \
            kan_act_store(xb.y, rowp_ + ((c0 + 16) ^ as_sw));                 \
            if ((ktv) + 2 < NKT)                                              \
                xb = *(const float2*)(xp + ((ktv) + 2) * 8);                  \
        }                                                                     \
        __builtin_amdgcn_s_setprio(1);                                        \
        _Pragma("unroll")                                                     \
        for (int ks_ = 0; ks_ < 2; ++ks_)                                     \
            _Pragma("unroll")                                                 \
            for (int m2_ = 0; m2_ < 4; ++m2_)                                 \
                _Pragma("unroll")                                             \
                for (int n2_ = 0; n2_ < 4; ++n2_)                             \
                    acc[m2_][n2_] = __builtin_amdgcn_mfma_f32_16x16x32_bf16(  \
                        af_[ks_][m2_], Bcur[ks_ * 4 + n2_], acc[m2_][n2_],    \
                        0, 0, 0);                                             \
        __builtin_amdgcn_s_setprio(0);                                        \
        asm volatile("s_waitcnt lgkmcnt(0)" ::: "memory");                    \
        __builtin_amdgcn_s_barrier();                                         \
    }

    for (int kt = 0; kt < NKT; kt += 2) {
        STEP(kt, Ba, Bb);
        STEP(kt + 1, Bb, Ba);
    }

    // ---- epilogue: C/D layout col = lane&15, row = (lane>>4)*4 + reg
    const int orow0 = row0 + fg * 4;
    const int ocol0 = col0 + wid * 64 + fr;
#pragma unroll
    for (int n2 = 0; n2 < 4; ++n2) {
        float bv = bias[ocol0 + n2 * 16];
#pragma unroll
        for (int m2 = 0; m2 < 4; ++m2) {
#pragma unroll
            for (int r = 0; r < 4; ++r) {
                y[(size_t)(orow0 + m2 * 16 + r) * DOUT + (ocol0 + n2 * 16)]
                    = acc[m2][n2][r] + bv;
            }
        }
    }
#undef STEP
#undef LOADB
}

extern "C" void kernel_launch(void* const* d_in, const int* in_sizes, int n_in,
                              void* d_out, int out_size, void* d_ws, size_t ws_size,
                              hipStream_t stream)
{
    const float* x          = (const float*)d_in[0];
    const float* coef       = (const float*)d_in[1];
    const float* scale_base = (const float*)d_in[2];
    const float* scale_sp   = (const float*)d_in[3];
    const float* bias       = (const float*)d_in[4];
    unsigned short* wt = (unsigned short*)d_ws;   // 4 MB packed wt2[nt][kt][ks][ol][fg]
    float* y = (float*)d_out;

    kan_prep<<<1024, 256, 0, stream>>>(coef, scale_base, scale_sp, wt);
    kan_gemm<<<512, 256, 0, stream>>>(x, wt, bias, y);
}